// Round 4
// baseline (176.469 us; speedup 1.0000x reference)
//
#include <hip/hip_runtime.h>
#include <hip/hip_fp16.h>

#define NMOL   32
#define NATOM  512
#define NPAIR  32768
#define NB     64
#define HIDDEN 256
#define TOTNATOM (NMOL * NATOM)
#define CAP    192   // stage capacity per wave (drain when base > 128)

// NOTE R4: plain atomicAdd(float*) on LDS expands to a CAS retry loop under
// default flags (no -munsafe-fp-atomics) -- ~240cy dependent DS round trips
// per wave-op. unsafeAtomicAdd lowers to native ds_add_f32.
__device__ __forceinline__ void lds_fadd(float* p, float v) { unsafeAtomicAdd(p, v); }

__device__ __forceinline__ void do_pair(unsigned dfp, unsigned pk, float cb, float wb,
                                        const float* __restrict__ cemb,
                                        float* __restrict__ dens, int lane) {
    __half2 hh = *reinterpret_cast<const __half2*>(&dfp);
    const float bd  = __low2float(hh);    // distance
    const float bfc = __high2float(hh);   // fc (0 for pad entries)
    const float ce  = cemb[(pk & 7u) * NB + lane];
    const float t   = bd - cb;
    lds_fadd(&dens[(int)(pk >> 3) * NB + lane], __expf(-wb * t * t) * bfc * ce);
}

// ---------------------------------------------------------------------------
// pair_kernel: grid = NMOL * nsub blocks, 1024 threads (16 waves)
// phase 1 (lane=pair): dist/cutoff + tv LDS atomics + ballot-compact staging
// phase 2 (lane=basis): counted drain loop, broadcast LDS reads
// flush: plain coalesced stores to a private per-block partial region
// ---------------------------------------------------------------------------
__global__ __launch_bounds__(1024) void pair_kernel(
    const float* __restrict__ cart, const float* __restrict__ shifts,
    const float* __restrict__ centers, const float* __restrict__ widths,
    const float* __restrict__ c_emb, const int* __restrict__ species,
    const int* __restrict__ atom_index,
    float* __restrict__ dens_part, float* __restrict__ tv_part, int nsub)
{
    __shared__ float dens[NATOM * NB];                         // 128 KB
    __shared__ float tv[NATOM * 3];                            // 6 KB
    __shared__ float cemb[8 * NB];                             // 2 KB
    __shared__ __align__(16) unsigned       s_df[16][CAP + 4]; // 12.25 KB
    __shared__ __align__(8)  unsigned short s_pk[16][CAP + 4]; // 6.1 KB

    const int tid = threadIdx.x;
    const int mol = blockIdx.x / nsub;
    const int sub = blockIdx.x % nsub;

    {
        float4 z = make_float4(0.f, 0.f, 0.f, 0.f);
        float4* d4 = reinterpret_cast<float4*>(dens);
        for (int i = tid; i < NATOM * NB / 4; i += 1024) d4[i] = z;
        for (int i = tid; i < NATOM * 3;  i += 1024) tv[i] = 0.f;
        if (tid < 8 * NB) cemb[tid] = c_emb[tid];
    }
    __syncthreads();

    const int lane = tid & 63;
    const int wave = tid >> 6;
    const float cb = centers[lane];   // lane = basis index in phase 2
    const float wb = widths[lane];

    const int*   ai0 = atom_index + (size_t)mol * NPAIR;
    const int*   ai1 = ai0 + (size_t)NMOL * NPAIR;
    const float* sh  = shifts + (size_t)mol * NPAIR * 3;
    const float* cm  = cart + (size_t)mol * NATOM * 3;
    const int*   sp  = species + (size_t)mol * NATOM;

    const int ppb  = NPAIR / nsub;          // pairs per block
    const int its  = ppb / 1024;            // phase-1 iterations
    const int pbase = sub * ppb + wave * (ppb >> 4);
    int base = 0;

    for (int it = 0; it < its; ++it) {
        const int p  = pbase + it * 64 + lane;   // lane = pair (phase 1)
        const int i0 = ai0[p];
        const int i1 = ai1[p];
        const float sx = sh[p * 3 + 0], sy = sh[p * 3 + 1], sz = sh[p * 3 + 2];
        const float m = (sx > -1e10f && sy > -1e10f && sz > -1e10f) ? 1.f : 0.f;
        const float dx = (cm[i0 * 3 + 0] - cm[i1 * 3 + 0] + sx) * m;
        const float dy = (cm[i0 * 3 + 1] - cm[i1 * 3 + 1] + sy) * m;
        const float dz = (cm[i0 * 3 + 2] - cm[i1 * 3 + 2] + sz) * m;
        const float d = sqrtf(dx * dx + dy * dy + dz * dz + 1e-12f);
        float fc = 0.f;
        if (d < 5.0f)
            fc = 0.5f * (__cosf(0.62831853071795864769f * d) + 1.f) * m;  // pi/RC

        // tot_vec segment-sum (all valid pairs, independent of cutoff)
        lds_fadd(&tv[i0 * 3 + 0], dx);
        lds_fadd(&tv[i0 * 3 + 1], dy);
        lds_fadd(&tv[i0 * 3 + 2], dz);

        // ballot-compact the in-cutoff pairs into per-wave staging
        const unsigned long long mask = __ballot(fc > 0.f);
        const int pos = __builtin_amdgcn_mbcnt_hi((unsigned)(mask >> 32),
                        __builtin_amdgcn_mbcnt_lo((unsigned)mask, 0u));
        if (fc > 0.f) {
            __half2 hh = __floats2half2_rn(d, fc);
            s_df[wave][base + pos] = *reinterpret_cast<unsigned*>(&hh);
            s_pk[wave][base + pos] = (unsigned short)((i0 << 3) | sp[i1]);
        }
        base += __popcll(mask);

        // drain (counted loop, unroll x4, broadcast b128/b64 LDS reads)
        if (it == its - 1 || base > 128) {
            if (lane < 4) { s_df[wave][base + lane] = 0u; s_pk[wave][base + lane] = 0; }
            for (int k = 0; k < base; k += 4) {
                const uint4   df4 = *reinterpret_cast<const uint4*>(&s_df[wave][k]);
                const ushort4 pk4 = *reinterpret_cast<const ushort4*>(&s_pk[wave][k]);
                do_pair(df4.x, pk4.x, cb, wb, cemb, dens, lane);
                do_pair(df4.y, pk4.y, cb, wb, cemb, dens, lane);
                do_pair(df4.z, pk4.z, cb, wb, cemb, dens, lane);
                do_pair(df4.w, pk4.w, cb, wb, cemb, dens, lane);
            }
            base = 0;
        }
    }
    __syncthreads();

    // flush: plain coalesced float4 stores into this block's private region
    float4* dg = reinterpret_cast<float4*>(dens_part + (size_t)blockIdx.x * NATOM * NB);
    const float4* ds4 = reinterpret_cast<const float4*>(dens);
    for (int i = tid; i < NATOM * NB / 4; i += 1024) dg[i] = ds4[i];
    float* tg = tv_part + (size_t)blockIdx.x * NATOM * 3;
    for (int i = tid; i < NATOM * 3; i += 1024) tg[i] = tv[i];
}

// ---------------------------------------------------------------------------
// reduce_kernel: sum nsub partials in place (into partial 0). Memory-bound.
// ---------------------------------------------------------------------------
__global__ __launch_bounds__(256) void reduce_kernel(float* dens_part, float* tv_part, int nsub)
{
    const int nd4 = NATOM * NB / 4;       // float4s per density partial-region
    const int nt  = NATOM * 3;            // floats per tv partial-region
    const int gid = blockIdx.x * 256 + threadIdx.x;
    const int nthreads = gridDim.x * 256;

    for (int i = gid; i < NMOL * nd4; i += nthreads) {
        const int m  = i / nd4;
        const int e  = i - m * nd4;
        float4* base0 = reinterpret_cast<float4*>(dens_part + (size_t)m * nsub * NATOM * NB);
        float4 acc = base0[e];
        for (int s = 1; s < nsub; ++s) {
            const float4 v = base0[(size_t)s * nd4 + e];
            acc.x += v.x; acc.y += v.y; acc.z += v.z; acc.w += v.w;
        }
        base0[e] = acc;
    }
    for (int i = gid; i < NMOL * nt; i += nthreads) {
        const int m = i / nt;
        const int e = i - m * nt;
        float* base0 = tv_part + (size_t)m * nsub * NATOM * 3;
        float acc = base0[e];
        for (int s = 1; s < nsub; ++s) acc += base0[(size_t)s * nt + e];
        base0[e] = acc;
    }
}

// ---------------------------------------------------------------------------
// nn_kernel: 1024 blocks x 256 threads; block = 16 atoms, thread = hidden unit
// ---------------------------------------------------------------------------
__global__ __launch_bounds__(256) void nn_kernel(
    const float* __restrict__ dens_part, const float* __restrict__ tv_part,
    const float* __restrict__ W1, const float* __restrict__ b1,
    const float* __restrict__ W2, const float* __restrict__ b2,
    float* __restrict__ dipole, int nsub)
{
    const int j    = threadIdx.x;       // hidden unit 0..255
    const int lane = j & 63;
    const int wave = j >> 6;
    const int a0   = blockIdx.x * 16;                 // global atom base
    const int mol  = a0 / NATOM;
    const int arem = a0 - mol * NATOM;                // atom base within molecule
    const float* density = dens_part + (size_t)mol * nsub * NATOM * NB + (size_t)arem * NB;
    const float* totvec  = tv_part   + (size_t)mol * nsub * NATOM * 3  + (size_t)arem * 3;

    float w1r[64];
#pragma unroll
    for (int b = 0; b < 64; ++b) w1r[b] = W1[b * HIDDEN + j];
    const float b1v = b1[j];
    const float w2v = W2[j];

    float con[16];
#pragma unroll
    for (int a = 0; a < 16; ++a) {
        const float* row = density + a * NB;          // block-uniform -> s_load
        float h0 = b1v, h1 = 0.f, h2 = 0.f, h3 = 0.f;
#pragma unroll
        for (int b = 0; b < 64; b += 4) {
            h0 = fmaf(row[b + 0], w1r[b + 0], h0);
            h1 = fmaf(row[b + 1], w1r[b + 1], h1);
            h2 = fmaf(row[b + 2], w1r[b + 2], h2);
            h3 = fmaf(row[b + 3], w1r[b + 3], h3);
        }
        const float h = (h0 + h1) + (h2 + h3);
        con[a] = (h / (1.f + __expf(-h))) * w2v;      // silu * W2
    }

    __shared__ float part[4][16];
#pragma unroll
    for (int a = 0; a < 16; ++a) {
        float v = con[a];
#pragma unroll
        for (int off = 32; off; off >>= 1) v += __shfl_down(v, off);
        if (lane == 0) part[wave][a] = v;
    }
    __syncthreads();

    if (j < 16) {
        const int a = j;
        const float out = part[0][a] + part[1][a] + part[2][a] + part[3][a] + b2[0];
        const float* tvp = totvec + a * 3;
        float px = out * tvp[0], py = out * tvp[1], pz = out * tvp[2];
#pragma unroll
        for (int off = 8; off; off >>= 1) {
            px += __shfl_down(px, off, 16);
            py += __shfl_down(py, off, 16);
            pz += __shfl_down(pz, off, 16);
        }
        if (a == 0) {
            unsafeAtomicAdd(&dipole[mol * 3 + 0], px);
            unsafeAtomicAdd(&dipole[mol * 3 + 1], py);
            unsafeAtomicAdd(&dipole[mol * 3 + 2], pz);
        }
    }
}

// ---------------------------------------------------------------------------
extern "C" void kernel_launch(void* const* d_in, const int* in_sizes, int n_in,
                              void* d_out, int out_size, void* d_ws, size_t ws_size,
                              hipStream_t stream)
{
    const float* cart       = (const float*)d_in[0];
    const float* shifts     = (const float*)d_in[1];
    const float* centers    = (const float*)d_in[2];
    const float* widths     = (const float*)d_in[3];
    const float* c_emb      = (const float*)d_in[4];
    const float* W1         = (const float*)d_in[5];
    const float* b1         = (const float*)d_in[6];
    const float* W2         = (const float*)d_in[7];
    const float* b2         = (const float*)d_in[8];
    const int*   species    = (const int*)d_in[10];
    const int*   atom_index = (const int*)d_in[11];

    int nsub = 8;
    while (nsub > 1 &&
           (size_t)nsub * TOTNATOM * (NB + 3) * sizeof(float) > ws_size) nsub >>= 1;

    float* dens_part = (float*)d_ws;                                  // [NMOL*nsub][NATOM*NB]
    float* tv_part   = dens_part + (size_t)NMOL * nsub * NATOM * NB;  // [NMOL*nsub][NATOM*3]
    float* dipole    = (float*)d_out;                                 // [32][3]

    hipMemsetAsync(d_out, 0, (size_t)out_size * sizeof(float), stream);

    hipLaunchKernelGGL(pair_kernel, dim3(NMOL * nsub), dim3(1024), 0, stream,
                       cart, shifts, centers, widths, c_emb, species, atom_index,
                       dens_part, tv_part, nsub);
    hipLaunchKernelGGL(reduce_kernel, dim3(1024), dim3(256), 0, stream,
                       dens_part, tv_part, nsub);
    hipLaunchKernelGGL(nn_kernel, dim3(TOTNATOM / 16), dim3(256), 0, stream,
                       dens_part, tv_part, W1, b1, W2, b2, dipole, nsub);
}

// Round 5
// 140.247 us; speedup vs baseline: 1.2583x; 1.2583x over previous
//
#include <hip/hip_runtime.h>

#define NMOL   32
#define NATOM  512
#define NPAIR  32768
#define NB     64
#define HIDDEN 256
#define TOTNATOM (NMOL * NATOM)

// ---------------------------------------------------------------------------
// K1 scatter: per pair -> 16B record {dx,dy,dz,spc} appended to center-atom
// bucket via global u32 cursor. 1024 blocks x 256 thr, 4 pairs/thread.
// ---------------------------------------------------------------------------
__global__ __launch_bounds__(256) void scatter_kernel(
    const float* __restrict__ cart, const float* __restrict__ shifts,
    const int* __restrict__ species, const int* __restrict__ atom_index,
    unsigned* __restrict__ cnt, uint4* __restrict__ rec, int cap)
{
    const int mol = blockIdx.x >> 5;          // 32 blocks per molecule
    const int sl  = blockIdx.x & 31;
    const int*   ai0 = atom_index + (size_t)mol * NPAIR;
    const int*   ai1 = ai0 + (size_t)NMOL * NPAIR;
    const float* sh  = shifts + (size_t)mol * NPAIR * 3;
    const float* cm  = cart + (size_t)mol * NATOM * 3;
    const int*   sp  = species + (size_t)mol * NATOM;
    const int base = sl * 1024;

#pragma unroll
    for (int k = 0; k < 4; ++k) {
        const int p  = base + k * 256 + threadIdx.x;
        const int i0 = ai0[p];
        const int i1 = ai1[p];
        const float sx = sh[p * 3 + 0], sy = sh[p * 3 + 1], sz = sh[p * 3 + 2];
        const bool valid = (sx > -1e10f) && (sy > -1e10f) && (sz > -1e10f);
        if (!valid) continue;                 // masked pairs contribute nothing
        const float dx = cm[i0 * 3 + 0] - cm[i1 * 3 + 0] + sx;
        const float dy = cm[i0 * 3 + 1] - cm[i1 * 3 + 1] + sy;
        const float dz = cm[i0 * 3 + 2] - cm[i1 * 3 + 2] + sz;
        const int ga = mol * NATOM + i0;      // global center atom
        const unsigned pos = atomicAdd(&cnt[ga], 1u);
        if (pos < (unsigned)cap)
            rec[(size_t)ga * cap + pos] =
                make_uint4(__float_as_uint(dx), __float_as_uint(dy),
                           __float_as_uint(dz), (unsigned)sp[i1]);
    }
}

// ---------------------------------------------------------------------------
// K2 gather: wave = atom, lane = basis. Stream the atom's contiguous records,
// recompute d/fc, accumulate density row in ONE register + tv in registers.
// No fp atomics, no big LDS -> high occupancy, VALU-bound.
// ---------------------------------------------------------------------------
__global__ __launch_bounds__(256) void gather_kernel(
    const unsigned* __restrict__ cnt, const uint4* __restrict__ rec,
    const float* __restrict__ centers, const float* __restrict__ widths,
    const float* __restrict__ c_emb,
    float* __restrict__ dens, float* __restrict__ tv, int cap)
{
    __shared__ float cemb[8 * NB];
    for (int i = threadIdx.x; i < 8 * NB; i += 256) cemb[i] = c_emb[i];
    __syncthreads();

    const int lane = threadIdx.x & 63;
    const int wave = threadIdx.x >> 6;
    const int a = blockIdx.x * 4 + wave;      // global atom
    const float cb = centers[lane];
    const float wb = widths[lane];

    const int n = min((int)cnt[a], cap);
    const uint4* r = rec + (size_t)a * cap;

    float acc = 0.f, tx = 0.f, ty = 0.f, tz = 0.f;
    for (int k = 0; k < n; ++k) {
        const uint4 q = r[k];                 // wave-uniform broadcast load
        const float dx = __uint_as_float(q.x);
        const float dy = __uint_as_float(q.y);
        const float dz = __uint_as_float(q.z);
        tx += dx; ty += dy; tz += dz;
        const float d = sqrtf(dx * dx + dy * dy + dz * dz + 1e-12f);
        if (d < 5.0f) {                       // wave-uniform branch
            const float fc = 0.5f * (__cosf(0.62831853071795864769f * d) + 1.f);
            const float t  = d - cb;
            acc = fmaf(__expf(-wb * t * t) * fc, cemb[(q.w & 7u) * NB + lane], acc);
        }
    }
    dens[(size_t)a * NB + lane] = acc;        // coalesced row store
    if (lane == 0) { tv[a * 3 + 0] = tx; tv[a * 3 + 1] = ty; tv[a * 3 + 2] = tz; }
}

// ---------------------------------------------------------------------------
// K3 nn: 1024 blocks x 256 threads; block = 16 atoms, thread = hidden unit
// ---------------------------------------------------------------------------
__global__ __launch_bounds__(256) void nn_kernel(
    const float* __restrict__ dens, const float* __restrict__ tv,
    const float* __restrict__ W1, const float* __restrict__ b1,
    const float* __restrict__ W2, const float* __restrict__ b2,
    float* __restrict__ dipole)
{
    const int j    = threadIdx.x;             // hidden unit 0..255
    const int lane = j & 63;
    const int wave = j >> 6;
    const int a0   = blockIdx.x * 16;         // global atom base

    float w1r[64];
#pragma unroll
    for (int b = 0; b < 64; ++b) w1r[b] = W1[b * HIDDEN + j];
    const float b1v = b1[j];
    const float w2v = W2[j];

    float con[16];
#pragma unroll
    for (int a = 0; a < 16; ++a) {
        const float* row = dens + (size_t)(a0 + a) * NB;   // block-uniform
        float h0 = b1v, h1 = 0.f, h2 = 0.f, h3 = 0.f;
#pragma unroll
        for (int b = 0; b < 64; b += 4) {
            h0 = fmaf(row[b + 0], w1r[b + 0], h0);
            h1 = fmaf(row[b + 1], w1r[b + 1], h1);
            h2 = fmaf(row[b + 2], w1r[b + 2], h2);
            h3 = fmaf(row[b + 3], w1r[b + 3], h3);
        }
        const float h = (h0 + h1) + (h2 + h3);
        con[a] = (h / (1.f + __expf(-h))) * w2v;           // silu * W2
    }

    __shared__ float part[4][16];
#pragma unroll
    for (int a = 0; a < 16; ++a) {
        float v = con[a];
#pragma unroll
        for (int off = 32; off; off >>= 1) v += __shfl_down(v, off);
        if (lane == 0) part[wave][a] = v;
    }
    __syncthreads();

    if (j < 16) {
        const int a = j;
        const float out = part[0][a] + part[1][a] + part[2][a] + part[3][a] + b2[0];
        const float* tvp = tv + (size_t)(a0 + a) * 3;
        float px = out * tvp[0], py = out * tvp[1], pz = out * tvp[2];
#pragma unroll
        for (int off = 8; off; off >>= 1) {
            px += __shfl_down(px, off, 16);
            py += __shfl_down(py, off, 16);
            pz += __shfl_down(pz, off, 16);
        }
        if (a == 0) {
            const int mol = blockIdx.x >> 5;  // 32 blocks per molecule
            unsafeAtomicAdd(&dipole[mol * 3 + 0], px);
            unsafeAtomicAdd(&dipole[mol * 3 + 1], py);
            unsafeAtomicAdd(&dipole[mol * 3 + 2], pz);
        }
    }
}

// ---------------------------------------------------------------------------
extern "C" void kernel_launch(void* const* d_in, const int* in_sizes, int n_in,
                              void* d_out, int out_size, void* d_ws, size_t ws_size,
                              hipStream_t stream)
{
    const float* cart       = (const float*)d_in[0];
    const float* shifts     = (const float*)d_in[1];
    const float* centers    = (const float*)d_in[2];
    const float* widths     = (const float*)d_in[3];
    const float* c_emb      = (const float*)d_in[4];
    const float* W1         = (const float*)d_in[5];
    const float* b1         = (const float*)d_in[6];
    const float* W2         = (const float*)d_in[7];
    const float* b2         = (const float*)d_in[8];
    const int*   species    = (const int*)d_in[10];
    const int*   atom_index = (const int*)d_in[11];

    // ws layout: dens | tv | cnt | rec
    float*    dens = (float*)d_ws;                                  // 4 MB
    float*    tvv  = dens + (size_t)TOTNATOM * NB;                  // 192 KB
    unsigned* cnt  = (unsigned*)(tvv + (size_t)TOTNATOM * 3);       // 64 KB
    uint4*    rec  = (uint4*)(cnt + TOTNATOM);
    const size_t base_b = (size_t)TOTNATOM * (NB + 3 + 1) * sizeof(float);
    int cap = (int)((ws_size - base_b) / ((size_t)TOTNATOM * sizeof(uint4)));
    if (cap > 192) cap = 192;      // mean 64, sigma 8 -> 192 is absurdly safe
    if (cap < 96)  cap = 96;       // floor; mean+4sigma

    float* dipole = (float*)d_out;
    hipMemsetAsync(cnt, 0, TOTNATOM * sizeof(unsigned), stream);
    hipMemsetAsync(d_out, 0, (size_t)out_size * sizeof(float), stream);

    hipLaunchKernelGGL(scatter_kernel, dim3(NMOL * 32), dim3(256), 0, stream,
                       cart, shifts, species, atom_index, cnt, rec, cap);
    hipLaunchKernelGGL(gather_kernel, dim3(TOTNATOM / 4), dim3(256), 0, stream,
                       cnt, rec, centers, widths, c_emb, dens, tvv, cap);
    hipLaunchKernelGGL(nn_kernel, dim3(TOTNATOM / 16), dim3(256), 0, stream,
                       dens, tvv, W1, b1, W2, b2, dipole);
}

// Round 6
// 81.108 us; speedup vs baseline: 2.1757x; 1.7291x over previous
//
#include <hip/hip_runtime.h>

#define NMOL   32
#define NATOM  512
#define NPAIR  32768
#define NB     64
#define HIDDEN 256
#define TOTNATOM (NMOL * NATOM)

// ---------------------------------------------------------------------------
// K1 scatter: per pair -> 16B record {dx,dy,dz,spc} appended to center-atom
// bucket via global u32 cursor. 1024 blocks x 256 thr, 4 pairs/thread.
// ---------------------------------------------------------------------------
__global__ __launch_bounds__(256) void scatter_kernel(
    const float* __restrict__ cart, const float* __restrict__ shifts,
    const int* __restrict__ species, const int* __restrict__ atom_index,
    unsigned* __restrict__ cnt, uint4* __restrict__ rec, int cap)
{
    const int mol = blockIdx.x >> 5;          // 32 blocks per molecule
    const int sl  = blockIdx.x & 31;
    const int*   ai0 = atom_index + (size_t)mol * NPAIR;
    const int*   ai1 = ai0 + (size_t)NMOL * NPAIR;
    const float* sh  = shifts + (size_t)mol * NPAIR * 3;
    const float* cm  = cart + (size_t)mol * NATOM * 3;
    const int*   sp  = species + (size_t)mol * NATOM;
    const int base = sl * 1024;

#pragma unroll
    for (int k = 0; k < 4; ++k) {
        const int p  = base + k * 256 + threadIdx.x;
        const int i0 = ai0[p];
        const int i1 = ai1[p];
        const float sx = sh[p * 3 + 0], sy = sh[p * 3 + 1], sz = sh[p * 3 + 2];
        const bool valid = (sx > -1e10f) && (sy > -1e10f) && (sz > -1e10f);
        if (!valid) continue;                 // masked pairs contribute nothing
        const float dx = cm[i0 * 3 + 0] - cm[i1 * 3 + 0] + sx;
        const float dy = cm[i0 * 3 + 1] - cm[i1 * 3 + 1] + sy;
        const float dz = cm[i0 * 3 + 2] - cm[i1 * 3 + 2] + sz;
        const int ga = mol * NATOM + i0;      // global center atom
        const unsigned pos = atomicAdd(&cnt[ga], 1u);
        if (pos < (unsigned)cap)
            rec[(size_t)ga * cap + pos] =
                make_uint4(__float_as_uint(dx), __float_as_uint(dy),
                           __float_as_uint(dz), (unsigned)sp[i1]);
    }
}

// ---------------------------------------------------------------------------
// K2 gather: wave = atom. Phase A (lane = record): coalesced record loads,
// parallel d/fc, tv lane-partials, ballot-compact in-cutoff {d, fc|spc} into
// per-wave LDS. Phase B (lane = basis): loop only the ~30% compacted records,
// ~10 instr each. Removes the 64x-redundant uniform d/fc chain of R5.
// ---------------------------------------------------------------------------
__global__ __launch_bounds__(256) void gather_kernel(
    const unsigned* __restrict__ cnt, const uint4* __restrict__ rec,
    const float* __restrict__ centers, const float* __restrict__ widths,
    const float* __restrict__ c_emb,
    float* __restrict__ dens, float* __restrict__ tv, int cap)
{
    __shared__ float  cemb[8 * NB];           // 2 KB
    __shared__ float2 srec[4][68];            // 2.2 KB (64 + 4 pad)
    for (int i = threadIdx.x; i < 8 * NB; i += 256) cemb[i] = c_emb[i];
    __syncthreads();

    const int lane = threadIdx.x & 63;
    const int wave = threadIdx.x >> 6;
    const int a = blockIdx.x * 4 + wave;      // global atom
    const float cb  = centers[lane];
    const float nwb = -widths[lane];

    const int n = min((int)cnt[a], cap);
    const uint4* r = rec + (size_t)a * cap;

    float acc = 0.f, tx = 0.f, ty = 0.f, tz = 0.f;

    for (int c0 = 0; c0 < n; c0 += 64) {
        const int k = c0 + lane;
        // phase A: lane = record (coalesced 16B/lane)
        uint4 q = make_uint4(0u, 0u, 0u, 0u);
        if (k < n) q = r[k];
        const float dx = __uint_as_float(q.x);
        const float dy = __uint_as_float(q.y);
        const float dz = __uint_as_float(q.z);
        tx += dx; ty += dy; tz += dz;
        const float d = sqrtf(dx * dx + dy * dy + dz * dz + 1e-12f);
        float fc = 0.f;
        if (k < n && d < 5.0f)
            fc = 0.5f * (__cosf(0.62831853071795864769f * d) + 1.f);  // pi/RC

        const unsigned long long mask = __ballot(fc > 0.f);
        const int pos = __builtin_amdgcn_mbcnt_hi((unsigned)(mask >> 32),
                        __builtin_amdgcn_mbcnt_lo((unsigned)mask, 0u));
        if (fc > 0.f) {
            // pack spc into fc's low 3 mantissa bits (<=2^-20 rel perturbation)
            const unsigned fb = (__float_as_uint(fc) & ~7u) | q.w;
            srec[wave][pos] = make_float2(d, __uint_as_float(fb));
        }
        const int m = (int)__popcll(mask);
        if (lane < 4) srec[wave][m + lane] = make_float2(0.f, 0.f);  // pad
        // same wave: compiler inserts lgkmcnt, no barrier needed

        // phase B: lane = basis, broadcast ds_read_b64 per record
        for (int j = 0; j < m; j += 4) {
#pragma unroll
            for (int u = 0; u < 4; ++u) {
                const float2 rr = srec[wave][j + u];
                const unsigned fb = __float_as_uint(rr.y);
                const float fcv = __uint_as_float(fb & ~7u);   // 0 for pads
                const float t = rr.x - cb;
                acc = fmaf(__expf(nwb * t * t) * fcv,
                           cemb[((fb & 7u) << 6) | lane], acc);
            }
        }
    }

    dens[(size_t)a * NB + lane] = acc;        // coalesced row store
#pragma unroll
    for (int off = 32; off; off >>= 1) {
        tx += __shfl_down(tx, off);
        ty += __shfl_down(ty, off);
        tz += __shfl_down(tz, off);
    }
    if (lane == 0) { tv[a * 3 + 0] = tx; tv[a * 3 + 1] = ty; tv[a * 3 + 2] = tz; }
}

// ---------------------------------------------------------------------------
// K3 nn: 1024 blocks x 256 threads; block = 16 atoms, thread = hidden unit
// ---------------------------------------------------------------------------
__global__ __launch_bounds__(256) void nn_kernel(
    const float* __restrict__ dens, const float* __restrict__ tv,
    const float* __restrict__ W1, const float* __restrict__ b1,
    const float* __restrict__ W2, const float* __restrict__ b2,
    float* __restrict__ dipole)
{
    const int j    = threadIdx.x;             // hidden unit 0..255
    const int lane = j & 63;
    const int wave = j >> 6;
    const int a0   = blockIdx.x * 16;         // global atom base

    float w1r[64];
#pragma unroll
    for (int b = 0; b < 64; ++b) w1r[b] = W1[b * HIDDEN + j];
    const float b1v = b1[j];
    const float w2v = W2[j];

    float con[16];
#pragma unroll
    for (int a = 0; a < 16; ++a) {
        const float* row = dens + (size_t)(a0 + a) * NB;   // block-uniform
        float h0 = b1v, h1 = 0.f, h2 = 0.f, h3 = 0.f;
#pragma unroll
        for (int b = 0; b < 64; b += 4) {
            h0 = fmaf(row[b + 0], w1r[b + 0], h0);
            h1 = fmaf(row[b + 1], w1r[b + 1], h1);
            h2 = fmaf(row[b + 2], w1r[b + 2], h2);
            h3 = fmaf(row[b + 3], w1r[b + 3], h3);
        }
        const float h = (h0 + h1) + (h2 + h3);
        con[a] = (h / (1.f + __expf(-h))) * w2v;           // silu * W2
    }

    __shared__ float part[4][16];
#pragma unroll
    for (int a = 0; a < 16; ++a) {
        float v = con[a];
#pragma unroll
        for (int off = 32; off; off >>= 1) v += __shfl_down(v, off);
        if (lane == 0) part[wave][a] = v;
    }
    __syncthreads();

    if (j < 16) {
        const int a = j;
        const float out = part[0][a] + part[1][a] + part[2][a] + part[3][a] + b2[0];
        const float* tvp = tv + (size_t)(a0 + a) * 3;
        float px = out * tvp[0], py = out * tvp[1], pz = out * tvp[2];
#pragma unroll
        for (int off = 8; off; off >>= 1) {
            px += __shfl_down(px, off, 16);
            py += __shfl_down(py, off, 16);
            pz += __shfl_down(pz, off, 16);
        }
        if (a == 0) {
            const int mol = blockIdx.x >> 5;  // 32 blocks per molecule
            unsafeAtomicAdd(&dipole[mol * 3 + 0], px);
            unsafeAtomicAdd(&dipole[mol * 3 + 1], py);
            unsafeAtomicAdd(&dipole[mol * 3 + 2], pz);
        }
    }
}

// ---------------------------------------------------------------------------
extern "C" void kernel_launch(void* const* d_in, const int* in_sizes, int n_in,
                              void* d_out, int out_size, void* d_ws, size_t ws_size,
                              hipStream_t stream)
{
    const float* cart       = (const float*)d_in[0];
    const float* shifts     = (const float*)d_in[1];
    const float* centers    = (const float*)d_in[2];
    const float* widths     = (const float*)d_in[3];
    const float* c_emb      = (const float*)d_in[4];
    const float* W1         = (const float*)d_in[5];
    const float* b1         = (const float*)d_in[6];
    const float* W2         = (const float*)d_in[7];
    const float* b2         = (const float*)d_in[8];
    const int*   species    = (const int*)d_in[10];
    const int*   atom_index = (const int*)d_in[11];

    // ws layout: dens | tv | cnt | rec
    float*    dens = (float*)d_ws;                                  // 4 MB
    float*    tvv  = dens + (size_t)TOTNATOM * NB;                  // 192 KB
    unsigned* cnt  = (unsigned*)(tvv + (size_t)TOTNATOM * 3);       // 64 KB
    uint4*    rec  = (uint4*)(cnt + TOTNATOM);
    const size_t base_b = (size_t)TOTNATOM * (NB + 3 + 1) * sizeof(float);
    int cap = (int)((ws_size - base_b) / ((size_t)TOTNATOM * sizeof(uint4)));
    if (cap > 192) cap = 192;      // mean 64, sigma 8 -> 192 is absurdly safe
    if (cap < 96)  cap = 96;       // floor; mean+4sigma

    float* dipole = (float*)d_out;
    hipMemsetAsync(cnt, 0, TOTNATOM * sizeof(unsigned), stream);
    hipMemsetAsync(d_out, 0, (size_t)out_size * sizeof(float), stream);

    hipLaunchKernelGGL(scatter_kernel, dim3(NMOL * 32), dim3(256), 0, stream,
                       cart, shifts, species, atom_index, cnt, rec, cap);
    hipLaunchKernelGGL(gather_kernel, dim3(TOTNATOM / 4), dim3(256), 0, stream,
                       cnt, rec, centers, widths, c_emb, dens, tvv, cap);
    hipLaunchKernelGGL(nn_kernel, dim3(TOTNATOM / 16), dim3(256), 0, stream,
                       dens, tvv, W1, b1, W2, b2, dipole);
}

// Round 7
// 71.523 us; speedup vs baseline: 2.4673x; 1.1340x over previous
//
#include <hip/hip_runtime.h>

#define NMOL   32
#define NATOM  512
#define NPAIR  32768
#define NB     64
#define HIDDEN 256
#define TOTNATOM (NMOL * NATOM)
#define NSUB   8
#define CAP2   64    // in-cutoff records/atom: mean ~17, max ~35 -> 64 safe

// ---------------------------------------------------------------------------
// K0: one launch zeroing cnt + dipole (replaces two hipMemsetAsync dispatches,
// one of which profiled at 40 us)
// ---------------------------------------------------------------------------
__global__ __launch_bounds__(256) void zero_kernel(unsigned* __restrict__ cnt,
                                                   float* __restrict__ dipole, int ndip)
{
    const int i = blockIdx.x * 256 + threadIdx.x;
    if (i < TOTNATOM) cnt[i] = 0u;
    if (i < ndip) dipole[i] = 0.f;
}

// ---------------------------------------------------------------------------
// K1 scatter: 256 blocks (mol x sub) x 1024 thr, 4 pairs/thread.
// tv accumulated in per-block LDS (6 KB, native ds_add_f32) -> tv_part.
// Only in-cutoff pairs (~26%) stored, as 8B {d, fc|spc} records.
// R6->R7: kills ~50 MB of scattered 64B-line writes (was the 42 us wall).
// ---------------------------------------------------------------------------
__global__ __launch_bounds__(1024) void scatter_kernel(
    const float* __restrict__ cart, const float* __restrict__ shifts,
    const int* __restrict__ species, const int* __restrict__ atom_index,
    unsigned* __restrict__ cnt, float2* __restrict__ rec,
    float* __restrict__ tv_part)
{
    __shared__ float tv[NATOM * 3];   // 6 KB
    const int tid = threadIdx.x;
    const int mol = blockIdx.x >> 3;
    const int sub = blockIdx.x & 7;

    for (int i = tid; i < NATOM * 3; i += 1024) tv[i] = 0.f;
    __syncthreads();

    const int*   ai0 = atom_index + (size_t)mol * NPAIR;
    const int*   ai1 = ai0 + (size_t)NMOL * NPAIR;
    const float* sh  = shifts + (size_t)mol * NPAIR * 3;
    const float* cm  = cart + (size_t)mol * NATOM * 3;
    const int*   sp  = species + (size_t)mol * NATOM;
    const int base = sub * 4096;

    for (int k = 0; k < 4; ++k) {
        const int p  = base + k * 1024 + tid;
        const int i0 = ai0[p];
        const int i1 = ai1[p];
        const float sx = sh[p * 3 + 0], sy = sh[p * 3 + 1], sz = sh[p * 3 + 2];
        if (!(sx > -1e10f && sy > -1e10f && sz > -1e10f)) continue;  // masked
        const float dx = cm[i0 * 3 + 0] - cm[i1 * 3 + 0] + sx;
        const float dy = cm[i0 * 3 + 1] - cm[i1 * 3 + 1] + sy;
        const float dz = cm[i0 * 3 + 2] - cm[i1 * 3 + 2] + sz;
        unsafeAtomicAdd(&tv[i0 * 3 + 0], dx);    // ds_add_f32
        unsafeAtomicAdd(&tv[i0 * 3 + 1], dy);
        unsafeAtomicAdd(&tv[i0 * 3 + 2], dz);
        const float d = sqrtf(dx * dx + dy * dy + dz * dz + 1e-12f);
        if (d < 5.0f) {
            const float fc = 0.5f * (__cosf(0.62831853071795864769f * d) + 1.f);
            // pack spc into fc's low 3 mantissa bits (<=2^-20 rel perturbation)
            const unsigned fb = (__float_as_uint(fc) & ~7u) | (unsigned)sp[i1];
            const int ga = mol * NATOM + i0;
            const unsigned pos = atomicAdd(&cnt[ga], 1u);
            if (pos < CAP2)
                rec[(size_t)ga * CAP2 + pos] = make_float2(d, __uint_as_float(fb));
        }
    }
    __syncthreads();

    float* tg = tv_part + (size_t)blockIdx.x * NATOM * 3;
    for (int i = tid; i < NATOM * 3; i += 1024) tg[i] = tv[i];
}

// ---------------------------------------------------------------------------
// K2 gather: wave = atom, lane = basis. Records already hold {d, fc|spc};
// ~17 broadcast 8B loads/atom, ~10 instr each. Also sums the 8 tv partials.
// ---------------------------------------------------------------------------
__global__ __launch_bounds__(256) void gather_kernel(
    const unsigned* __restrict__ cnt, const float2* __restrict__ rec,
    const float* __restrict__ centers, const float* __restrict__ widths,
    const float* __restrict__ c_emb, const float* __restrict__ tv_part,
    float* __restrict__ dens, float* __restrict__ tv)
{
    __shared__ float cemb[8 * NB];
    for (int i = threadIdx.x; i < 8 * NB; i += 256) cemb[i] = c_emb[i];
    __syncthreads();

    const int lane = threadIdx.x & 63;
    const int wave = threadIdx.x >> 6;
    const int a = blockIdx.x * 4 + wave;      // global atom
    const float cb  = centers[lane];
    const float nwb = -widths[lane];

    const int n = min((int)cnt[a], CAP2);
    const float2* r = rec + (size_t)a * CAP2;

    float acc = 0.f;
    int k = 0;
    for (; k + 2 <= n; k += 2) {              // 2 independent chains
        const float2 r0 = r[k], r1 = r[k + 1];
        const unsigned f0 = __float_as_uint(r0.y), f1 = __float_as_uint(r1.y);
        const float t0 = r0.x - cb, t1 = r1.x - cb;
        acc = fmaf(__expf(nwb * t0 * t0) * __uint_as_float(f0 & ~7u),
                   cemb[((f0 & 7u) << 6) | lane], acc);
        acc = fmaf(__expf(nwb * t1 * t1) * __uint_as_float(f1 & ~7u),
                   cemb[((f1 & 7u) << 6) | lane], acc);
    }
    if (k < n) {
        const float2 r0 = r[k];
        const unsigned f0 = __float_as_uint(r0.y);
        const float t0 = r0.x - cb;
        acc = fmaf(__expf(nwb * t0 * t0) * __uint_as_float(f0 & ~7u),
                   cemb[((f0 & 7u) << 6) | lane], acc);
    }
    dens[(size_t)a * NB + lane] = acc;        // coalesced row store

    if (lane < 3) {                           // sum the 8 tv block-partials
        const int mol = a >> 9, ra = a & 511;
        float s = 0.f;
#pragma unroll
        for (int sb = 0; sb < NSUB; ++sb)
            s += tv_part[((size_t)(mol * NSUB + sb) * NATOM + ra) * 3 + lane];
        tv[a * 3 + lane] = s;
    }
}

// ---------------------------------------------------------------------------
// K3 nn: 1024 blocks x 256 threads; block = 16 atoms, thread = hidden unit
// ---------------------------------------------------------------------------
__global__ __launch_bounds__(256) void nn_kernel(
    const float* __restrict__ dens, const float* __restrict__ tv,
    const float* __restrict__ W1, const float* __restrict__ b1,
    const float* __restrict__ W2, const float* __restrict__ b2,
    float* __restrict__ dipole)
{
    const int j    = threadIdx.x;             // hidden unit 0..255
    const int lane = j & 63;
    const int wave = j >> 6;
    const int a0   = blockIdx.x * 16;         // global atom base

    float w1r[64];
#pragma unroll
    for (int b = 0; b < 64; ++b) w1r[b] = W1[b * HIDDEN + j];
    const float b1v = b1[j];
    const float w2v = W2[j];

    float con[16];
#pragma unroll
    for (int a = 0; a < 16; ++a) {
        const float* row = dens + (size_t)(a0 + a) * NB;   // block-uniform
        float h0 = b1v, h1 = 0.f, h2 = 0.f, h3 = 0.f;
#pragma unroll
        for (int b = 0; b < 64; b += 4) {
            h0 = fmaf(row[b + 0], w1r[b + 0], h0);
            h1 = fmaf(row[b + 1], w1r[b + 1], h1);
            h2 = fmaf(row[b + 2], w1r[b + 2], h2);
            h3 = fmaf(row[b + 3], w1r[b + 3], h3);
        }
        const float h = (h0 + h1) + (h2 + h3);
        con[a] = (h / (1.f + __expf(-h))) * w2v;           // silu * W2
    }

    __shared__ float part[4][16];
#pragma unroll
    for (int a = 0; a < 16; ++a) {
        float v = con[a];
#pragma unroll
        for (int off = 32; off; off >>= 1) v += __shfl_down(v, off);
        if (lane == 0) part[wave][a] = v;
    }
    __syncthreads();

    if (j < 16) {
        const int a = j;
        const float out = part[0][a] + part[1][a] + part[2][a] + part[3][a] + b2[0];
        const float* tvp = tv + (size_t)(a0 + a) * 3;
        float px = out * tvp[0], py = out * tvp[1], pz = out * tvp[2];
#pragma unroll
        for (int off = 8; off; off >>= 1) {
            px += __shfl_down(px, off, 16);
            py += __shfl_down(py, off, 16);
            pz += __shfl_down(pz, off, 16);
        }
        if (a == 0) {
            const int mol = blockIdx.x >> 5;  // 32 blocks per molecule
            unsafeAtomicAdd(&dipole[mol * 3 + 0], px);
            unsafeAtomicAdd(&dipole[mol * 3 + 1], py);
            unsafeAtomicAdd(&dipole[mol * 3 + 2], pz);
        }
    }
}

// ---------------------------------------------------------------------------
extern "C" void kernel_launch(void* const* d_in, const int* in_sizes, int n_in,
                              void* d_out, int out_size, void* d_ws, size_t ws_size,
                              hipStream_t stream)
{
    const float* cart       = (const float*)d_in[0];
    const float* shifts     = (const float*)d_in[1];
    const float* centers    = (const float*)d_in[2];
    const float* widths     = (const float*)d_in[3];
    const float* c_emb      = (const float*)d_in[4];
    const float* W1         = (const float*)d_in[5];
    const float* b1         = (const float*)d_in[6];
    const float* W2         = (const float*)d_in[7];
    const float* b2         = (const float*)d_in[8];
    const int*   species    = (const int*)d_in[10];
    const int*   atom_index = (const int*)d_in[11];

    // ws layout: dens(4MB) | tv(192KB) | tv_part(1.5MB) | cnt(64KB) | rec(8MB)
    float*    dens    = (float*)d_ws;
    float*    tvv     = dens + (size_t)TOTNATOM * NB;
    float*    tv_part = tvv + (size_t)TOTNATOM * 3;
    unsigned* cnt     = (unsigned*)(tv_part + (size_t)NMOL * NSUB * NATOM * 3);
    float2*   rec     = (float2*)(cnt + TOTNATOM);
    float*    dipole  = (float*)d_out;

    hipLaunchKernelGGL(zero_kernel, dim3((TOTNATOM + 255) / 256), dim3(256), 0, stream,
                       cnt, dipole, out_size);
    hipLaunchKernelGGL(scatter_kernel, dim3(NMOL * NSUB), dim3(1024), 0, stream,
                       cart, shifts, species, atom_index, cnt, rec, tv_part);
    hipLaunchKernelGGL(gather_kernel, dim3(TOTNATOM / 4), dim3(256), 0, stream,
                       cnt, rec, centers, widths, c_emb, tv_part, dens, tvv);
    hipLaunchKernelGGL(nn_kernel, dim3(TOTNATOM / 16), dim3(256), 0, stream,
                       dens, tvv, W1, b1, W2, b2, dipole);
}